// Round 2
// baseline (7400.869 us; speedup 1.0000x reference)
//
#include <hip/hip_runtime.h>
#include <hip/hip_fp16.h>

#define DEVINL __device__ __forceinline__

constexpr int B = 256, S = 512;
constexpr int H0 = 64, H1 = 128, H2 = 256;

typedef _Float16 h2v __attribute__((ext_vector_type(2)));

DEVINL h2v as_h2(unsigned u) { union { unsigned u; h2v h; } x; x.u = u; return x.h; }
DEVINL float fexp2(float x) { return __builtin_amdgcn_exp2f(x); }
DEVINL float frcp(float x) { return __builtin_amdgcn_rcpf(x); }
DEVINL float fsig(float x) { return frcp(1.f + fexp2(-1.44269504088896f * x)); }
DEVINL float ftanh_(float x) { return 1.f - 2.f * frcp(1.f + fexp2(2.88539008177793f * x)); }
DEVINL float fdot2(unsigned a, unsigned b, float c) {
  return __builtin_amdgcn_fdot2(as_h2(a), as_h2(b), c, false);
}

// Pack Whh [4H][H] fp32 (torch gate order i,f,g,o) into fp16 k-pair layout:
// wt[kp*H + t] = uint4{ q: half2(W[q*H+t][2kp], W[q*H+t][2kp+1]) }
__global__ __launch_bounds__(256) void pack_whh(const float* __restrict__ w,
                                                uint4* __restrict__ wt, int H) {
  int i = blockIdx.x * 256 + threadIdx.x;
  int tot = (H / 2) * H;
  if (i >= tot) return;
  int t = i % H, kp = i / H;
  unsigned r[4];
#pragma unroll
  for (int q = 0; q < 4; ++q) {
    float f0 = w[(size_t)(q * H + t) * H + 2 * kp];
    float f1 = w[(size_t)(q * H + t) * H + 2 * kp + 1];
    unsigned lo = __half_as_ushort(__float2half_rn(f0));
    unsigned hi = __half_as_ushort(__float2half_rn(f1));
    r[q] = (hi << 16) | lo;
  }
  uint4 o4; o4.x = r[0]; o4.y = r[1]; o4.z = r[2]; o4.w = r[3];
  wt[i] = o4;
}

// Input GEMM: pre[b*Sc+tl][j] = sum_k x[b][t0+tl][k]*Wih[j][k] + bih[j] + bhh[j]
template <int K>
__global__ __launch_bounds__(256) void ingemm(const float* __restrict__ x,
    const float* __restrict__ wih, const float* __restrict__ bih,
    const float* __restrict__ bhh, float* __restrict__ pre,
    int N, int Sc, int t0) {
  constexpr int KT = (K < 64) ? K : 64;
  constexpr int KTB = KT / 4;
  __shared__ float4 As[64 * KTB];
  __shared__ float4 Bs[64 * KTB];
  const int tid = threadIdx.x;
  const int rp0 = blockIdx.x * 64;
  const int n0 = blockIdx.y * 64;
  const int tn = tid & 15, tm = tid >> 4;
  float acc[4][4] = {};
  for (int ks = 0; ks < K; ks += KT) {
    for (int i = tid; i < 64 * KTB; i += 256) {
      int rr = i / KTB, kq = i % KTB;
      int rp = rp0 + rr;
      int b = rp / Sc, tl = rp - b * Sc;
      const float* srcx = x + (size_t)(b * S + t0 + tl) * K + ks + 4 * kq;
      As[rr * KTB + (kq ^ ((rr >> 2) & 7))] = *reinterpret_cast<const float4*>(srcx);
      const float* srcw = wih + (size_t)(n0 + rr) * K + ks + 4 * kq;
      Bs[rr * KTB + (kq ^ ((rr >> 2) & 7))] = *reinterpret_cast<const float4*>(srcw);
    }
    __syncthreads();
#pragma unroll 8
    for (int kb = 0; kb < KTB; ++kb) {
      float4 a[4], bb[4];
#pragma unroll
      for (int i2 = 0; i2 < 4; ++i2) a[i2] = As[(4 * tm + i2) * KTB + (kb ^ (tm & 7))];
#pragma unroll
      for (int j = 0; j < 4; ++j) bb[j] = Bs[(4 * tn + j) * KTB + (kb ^ (tn & 7))];
#pragma unroll
      for (int i2 = 0; i2 < 4; ++i2)
#pragma unroll
        for (int j = 0; j < 4; ++j) {
          acc[i2][j] += a[i2].x * bb[j].x;
          acc[i2][j] += a[i2].y * bb[j].y;
          acc[i2][j] += a[i2].z * bb[j].z;
          acc[i2][j] += a[i2].w * bb[j].w;
        }
    }
    __syncthreads();
  }
  float4 bi = *reinterpret_cast<const float4*>(bih + n0 + 4 * tn);
  float4 bh = *reinterpret_cast<const float4*>(bhh + n0 + 4 * tn);
  float bx = bi.x + bh.x, by = bi.y + bh.y, bz = bi.z + bh.z, bw = bi.w + bh.w;
#pragma unroll
  for (int i2 = 0; i2 < 4; ++i2) {
    int rp = rp0 + 4 * tm + i2;
    float4 v; v.x = acc[i2][0] + bx; v.y = acc[i2][1] + by;
    v.z = acc[i2][2] + bz; v.w = acc[i2][3] + bw;
    *reinterpret_cast<float4*>(pre + (size_t)rp * N + n0 + 4 * tn) = v;
  }
}

template <int ROWS>
DEVINL void dot_step(uint4 w, const unsigned* hp, float* acc) {
  unsigned hh[ROWS];
  if constexpr (ROWS == 4) {
    uint4 h4 = *reinterpret_cast<const uint4*>(hp);
    hh[0] = h4.x; hh[1] = h4.y; hh[2] = h4.z; hh[3] = h4.w;
  } else if constexpr (ROWS == 2) {
    uint2 h2 = *reinterpret_cast<const uint2*>(hp);
    hh[0] = h2.x; hh[1] = h2.y;
  } else {
    hh[0] = hp[0];
  }
  const unsigned* wq = reinterpret_cast<const unsigned*>(&w);
#pragma unroll
  for (int q = 0; q < 4; ++q)
#pragma unroll
    for (int r = 0; r < ROWS; ++r)
      acc[q * ROWS + r] = fdot2(wq[q], hh[r], acc[q * ROWS + r]);
}

// Recurrent scan. THREADS = H*KAP. thread tid -> (t = tid/KAP channel, kap = tid%KAP).
// kap lives in the LOW lane bits -> k-split reduction is an in-wave shfl_xor butterfly.
// Each thread's kp set: kp = kap + KAP*i, i in [0, KP/KAP). First KPLI i's are
// LDS-resident weights, rest streamed from L2 in 8-deep batches.
// Gate math distributed across kap: thread handles batch row rr = kap % ROWS.
// h transported as packed fp16 pairs in LDS (h2bu), c stays in registers.
template <int H, int KAP, int KPLI, int ROWS, int THREADS, bool L2L>
__global__ __launch_bounds__(THREADS, 4) void scan(
    const uint4* __restrict__ wt, const float* __restrict__ pre,
    float* __restrict__ xout, float* __restrict__ out,
    const float* __restrict__ wl, const float* __restrict__ blp,
    float* __restrict__ sth, float* __restrict__ stc,
    int Sc, int t0, int first) {
  constexpr int KP = H / 2;
  constexpr int KPT = KP / KAP;
  constexpr int KPL = KAP * KPLI;
  constexpr int NACC = 4 * ROWS;
  __shared__ uint4 wlds[KPL * (H + 1)];
  __shared__ unsigned h2bu[KP * ROWS + 16];
  __shared__ float hsf[L2L ? 4 * H : 1];
  __shared__ float wls[L2L ? H : 1];

  const int tid = threadIdx.x;
  const int t = tid / KAP;
  const int kap = tid % KAP;
  const int rr = kap % ROWS;
  const int b0 = blockIdx.x * ROWS;

  auto hidx = [](int kp) { return kp * ROWS + ((kp >> 5) << 2); };

  for (int i = tid; i < KPL * H; i += THREADS) {
    int kp = i / H, tt = i % H;
    wlds[kp * (H + 1) + tt] = wt[i];
  }
  if (L2L)
    for (int i = tid; i < H; i += THREADS) wls[i] = wl[i];

  float cst = 0.f, hst = 0.f;
  if (!first) {
    hst = sth[(size_t)(b0 + rr) * H + t];
    cst = stc[(size_t)(b0 + rr) * H + t];
  }
  if (kap < ROWS) {
    reinterpret_cast<__half*>(&h2bu[hidx(t >> 1) + rr])[t & 1] = __float2half_rn(hst);
    if (L2L) hsf[rr * H + t] = hst;
  }
  __syncthreads();

  const float bl0 = L2L ? blp[0] : 0.f;
  const size_t prow = (size_t)(b0 + rr) * Sc * (4 * H) + t;
  float pg[4], pgN[4];
  {
    const float* pp = pre + prow;
    pg[0] = pp[0]; pg[1] = pp[H]; pg[2] = pp[2 * H]; pg[3] = pp[3 * H];
  }

  for (int tl = 0; tl < Sc; ++tl) {
    if (tl + 1 < Sc) {  // software-prefetch next step's preactivations (HBM latency cover)
      const float* pp = pre + prow + (size_t)(tl + 1) * (4 * H);
      pgN[0] = pp[0]; pgN[1] = pp[H]; pgN[2] = pp[2 * H]; pgN[3] = pp[3 * H];
    }
    float acc[NACC];
#pragma unroll
    for (int j = 0; j < NACC; ++j) acc[j] = 0.f;
    // LDS-resident weights
#pragma unroll
    for (int i = 0; i < ((KPLI < KPT) ? KPLI : KPT); ++i) {
      int kp = kap + KAP * i;
      uint4 w = wlds[kp * (H + 1) + t];
      dot_step<ROWS>(w, &h2bu[hidx(kp)], acc);
    }
    // streamed weights, 8-deep load batches for memory-level parallelism
    for (int i0 = KPLI; i0 < KPT; i0 += 8) {
      uint4 wb[8];
#pragma unroll
      for (int j = 0; j < 8; ++j)
        if (i0 + j < KPT) wb[j] = wt[(size_t)(kap + KAP * (i0 + j)) * H + t];
#pragma unroll
      for (int j = 0; j < 8; ++j)
        if (i0 + j < KPT) dot_step<ROWS>(wb[j], &h2bu[hidx(kap + KAP * (i0 + j))], acc);
    }
    // in-wave butterfly over the kap split (kap = low lane bits)
#pragma unroll
    for (int m = 1; m < KAP; m <<= 1)
#pragma unroll
      for (int j = 0; j < NACC; ++j) acc[j] += __shfl_xor(acc[j], m);

    float gi = fsig(pg[0] + acc[0 * ROWS + rr]);
    float gf = fsig(pg[1] + acc[1 * ROWS + rr]);
    float gg = ftanh_(pg[2] + acc[2 * ROWS + rr]);
    float go = fsig(pg[3] + acc[3 * ROWS + rr]);
    cst = gf * cst + gi * gg;
    float hv = go * ftanh_(cst);
    hst = hv;
    __syncthreads();  // A: everyone done reading h2bu for this step
    if (kap < ROWS) {
      reinterpret_cast<__half*>(&h2bu[hidx(t >> 1) + rr])[t & 1] = __float2half_rn(hv);
      if (L2L) hsf[rr * H + t] = hv;
      else xout[((size_t)(b0 + rr) * S + (t0 + tl)) * H + t] = hv;
    }
    __syncthreads();  // B: h2bu ready for next step
    if (L2L) {
      if (tid < 256) {
        int r = tid >> 6, c0 = tid & 63;
        float s = hsf[r * H + c0] * wls[c0] + hsf[r * H + c0 + 64] * wls[c0 + 64] +
                  hsf[r * H + c0 + 128] * wls[c0 + 128] +
                  hsf[r * H + c0 + 192] * wls[c0 + 192];
#pragma unroll
        for (int off = 32; off; off >>= 1) s += __shfl_down(s, off);
        if (c0 == 0) out[(size_t)(b0 + r) * S + (t0 + tl)] = ftanh_(s + bl0);
      }
    }
#pragma unroll
    for (int q = 0; q < 4; ++q) pg[q] = pgN[q];
  }
  if (kap < ROWS) {
    sth[(size_t)(b0 + rr) * H + t] = hst;
    stc[(size_t)(b0 + rr) * H + t] = cst;
  }
}

extern "C" void kernel_launch(void* const* d_in, const int* in_sizes, int n_in,
                              void* d_out, int out_size, void* d_ws, size_t ws_size,
                              hipStream_t stream) {
  (void)in_sizes; (void)n_in; (void)out_size;
  const float* noise = (const float*)d_in[0];
  const float* Wih0 = (const float*)d_in[1];
  const float* Whh0 = (const float*)d_in[2];
  const float* bih0 = (const float*)d_in[3];
  const float* bhh0 = (const float*)d_in[4];
  const float* Wih1 = (const float*)d_in[5];
  const float* Whh1 = (const float*)d_in[6];
  const float* bih1 = (const float*)d_in[7];
  const float* bhh1 = (const float*)d_in[8];
  const float* Wih2 = (const float*)d_in[9];
  const float* Whh2 = (const float*)d_in[10];
  const float* bih2 = (const float*)d_in[11];
  const float* bhh2 = (const float*)d_in[12];
  const float* Wl = (const float*)d_in[13];
  const float* bl = (const float*)d_in[14];
  float* out = (float*)d_out;

  char* p = (char*)d_ws;
  auto alloc = [&](size_t bytes) {
    char* r = p;
    p += (bytes + 255) & ~(size_t)255;
    return r;
  };
  uint4* wt0 = (uint4*)alloc((size_t)(H0 / 2) * H0 * 16);
  uint4* wt1 = (uint4*)alloc((size_t)(H1 / 2) * H1 * 16);
  uint4* wt2 = (uint4*)alloc((size_t)(H2 / 2) * H2 * 16);
  float* sh0 = (float*)alloc((size_t)B * H0 * 4);
  float* sc0 = (float*)alloc((size_t)B * H0 * 4);
  float* sh1 = (float*)alloc((size_t)B * H1 * 4);
  float* sc1 = (float*)alloc((size_t)B * H1 * 4);
  float* sh2 = (float*)alloc((size_t)B * H2 * 4);
  float* sc2 = (float*)alloc((size_t)B * H2 * 4);
  float* x1 = (float*)alloc((size_t)B * S * H0 * 4);
  float* x2 = (float*)alloc((size_t)B * S * H1 * 4);
  size_t fixed = (size_t)(p - (char*)d_ws);
  int Sc = 128;  // time-chunk bounds the pre-buffer and keeps it L3-resident
  while (Sc > 16 && fixed + (size_t)B * Sc * 1024 * 4 > ws_size) Sc >>= 1;
  float* pre = (float*)alloc((size_t)B * Sc * 1024 * 4);

  pack_whh<<<((H0 / 2) * H0 + 255) / 256, 256, 0, stream>>>(Whh0, wt0, H0);
  pack_whh<<<((H1 / 2) * H1 + 255) / 256, 256, 0, stream>>>(Whh1, wt1, H1);
  pack_whh<<<((H2 / 2) * H2 + 255) / 256, 256, 0, stream>>>(Whh2, wt2, H2);

  for (int c = 0; c < S / Sc; ++c) {
    int t0 = c * Sc;
    int mt = B * Sc / 64;
    ingemm<32><<<dim3(mt, 4), 256, 0, stream>>>(noise, Wih0, bih0, bhh0, pre, 256, Sc, t0);
    // H=64: all 32 k-pairs LDS-resident, 256 WGs x 1 row (full CU coverage)
    scan<64, 4, 8, 1, 256, false><<<256, 256, 0, stream>>>(
        wt0, pre, x1, nullptr, nullptr, nullptr, sh0, sc0, Sc, t0, c == 0);
    ingemm<64><<<dim3(mt, 8), 256, 0, stream>>>(x1, Wih1, bih1, bhh1, pre, 512, Sc, t0);
    // H=128: 128 WGs x 2 rows x 1024 thr, 24/64 kp in LDS, rest L2-streamed
    scan<128, 8, 3, 2, 1024, false><<<128, 1024, 0, stream>>>(
        wt1, pre, x2, nullptr, nullptr, nullptr, sh1, sc1, Sc, t0, c == 0);
    ingemm<128><<<dim3(mt, 16), 256, 0, stream>>>(x2, Wih2, bih2, bhh2, pre, 1024, Sc, t0);
    // H=256: 64 WGs x 4 rows x 1024 thr (16 waves/CU), 12/128 kp LDS, fused final linear
    scan<256, 4, 3, 4, 1024, true><<<64, 1024, 0, stream>>>(
        wt2, pre, nullptr, out, Wl, bl, sh2, sc2, Sc, t0, c == 0);
  }
}

// Round 3
// 3894.241 us; speedup vs baseline: 1.9005x; 1.9005x over previous
//
#include <hip/hip_runtime.h>
#include <hip/hip_fp16.h>

#define DEVINL __device__ __forceinline__

constexpr int B = 256, S = 512;
constexpr int H0 = 64, H1 = 128, H2 = 256;

typedef _Float16 f16x8 __attribute__((ext_vector_type(8)));
typedef float f32x4 __attribute__((ext_vector_type(4)));
typedef _Float16 h2v __attribute__((ext_vector_type(2)));

DEVINL float fexp2(float x) { return __builtin_amdgcn_exp2f(x); }
DEVINL float frcp(float x) { return __builtin_amdgcn_rcpf(x); }
DEVINL float fsig(float x) { return frcp(1.f + fexp2(-1.44269504088896f * x)); }
DEVINL float ftanh_(float x) { return 1.f - 2.f * frcp(1.f + fexp2(2.88539008177793f * x)); }
DEVINL h2v as_h2(unsigned u) { union { unsigned u; h2v h; } x; x.u = u; return x.h; }
DEVINL float fdot2(unsigned a, unsigned b, float c) {
  return __builtin_amdgcn_fdot2(as_h2(a), as_h2(b), c, false);
}
union FU { uint4 u; f16x8 h; };
DEVINL f16x8 as_f16x8(uint4 u) { FU x; x.u = u; return x.h; }

// Row permutation: r' = mt*16 + quad*4 + reg  ->  channel = r'>>2, gate = r'&3
// orig torch row = gate*H + channel. This puts each channel's (i,f,g,o) quad
// into ONE lane of the mfma C-fragment (C: col=lane&15, row=(lane>>4)*4+reg).

// Pack Whh (fp32 [4H][H]) into fp16 A-fragment order:
// wpack[(mt*KT + kt)*64 + lane] = 8 halves of W'[mt*16 + (lane&15)][kt*32 + (lane>>4)*8 + j]
__global__ __launch_bounds__(256) void pack_whh_frag(const float* __restrict__ whh,
                                                     uint4* __restrict__ wpack,
                                                     int H, int MT, int KT) {
  int o = blockIdx.x * 256 + threadIdx.x;
  if (o >= MT * KT * 64) return;
  int lane = o & 63, fk = o >> 6;
  int kt = fk % KT, mt = fk / KT;
  int rp = mt * 16 + (lane & 15);
  int orig = (rp & 3) * H + (rp >> 2);
  int k0 = kt * 32 + (lane >> 4) * 8;
  unsigned r[4];
#pragma unroll
  for (int p = 0; p < 4; ++p) {
    unsigned lo = __half_as_ushort(__float2half_rn(whh[(size_t)orig * H + k0 + 2 * p]));
    unsigned hi = __half_as_ushort(__float2half_rn(whh[(size_t)orig * H + k0 + 2 * p + 1]));
    r[p] = lo | (hi << 16);
  }
  uint4 v; v.x = r[0]; v.y = r[1]; v.z = r[2]; v.w = r[3];
  wpack[o] = v;
}

// Permute Wih rows (+ fold bias sum) into the same row order.
__global__ __launch_bounds__(256) void pack_wih(const float* __restrict__ wih,
    const float* __restrict__ bih, const float* __restrict__ bhh,
    float* __restrict__ wihP, float* __restrict__ bsum, int H, int K) {
  int idx = blockIdx.x * 256 + threadIdx.x;
  if (idx >= 4 * H * K) return;
  int rp = idx / K, k = idx % K;
  int orig = (rp & 3) * H + (rp >> 2);
  wihP[idx] = wih[(size_t)orig * K + k];
  if (k == 0) bsum[rp] = bih[orig] + bhh[orig];
}

__global__ void pack_wl(const float* __restrict__ wl, unsigned* __restrict__ wlp, int HP) {
  int i = threadIdx.x;
  if (i < HP) {
    unsigned lo = __half_as_ushort(__float2half_rn(wl[2 * i]));
    unsigned hi = __half_as_ushort(__float2half_rn(wl[2 * i + 1]));
    wlp[i] = lo | (hi << 16);
  }
}

// Input GEMM. Tile = 16 batch x 4 timesteps (64 rows) x 64 permuted-gate cols.
// Output written directly in mfma C-frag layout:
// preT[(((bt*Sc + t)*MT + mt)*64 + quad*16 + nlo)*4 + reg] (f32)
template <typename XT, int K>
__global__ __launch_bounds__(256) void ingemm(const XT* __restrict__ x,
    const float* __restrict__ wihP, const float* __restrict__ bsum,
    float* __restrict__ preT, int MT, int Sc, int t0) {
  constexpr int KTC = (K < 64) ? K : 64;
  constexpr int KTB = KTC / 4;
  __shared__ float4 As[64 * KTB];
  __shared__ float4 Bs[64 * KTB];
  __shared__ float tile[64 * 72];
  const int tid = threadIdx.x;
  const int bt = blockIdx.x & 15;
  const int tlb = (blockIdx.x >> 4) * 4;
  const int n0 = blockIdx.y * 64;
  const int tn = tid & 15, tm = tid >> 4;
  float acc[4][4] = {};
  for (int ks = 0; ks < K; ks += KTC) {
    for (int i = tid; i < 64 * KTB; i += 256) {
      int rr = i / KTB, kq = i % KTB;
      int b = bt * 16 + (rr & 15), tl = tlb + (rr >> 4);
      float4 xa;
      if constexpr (sizeof(XT) == 2) {
        const __half* sp = (const __half*)x + ((size_t)b * S + t0 + tl) * K + ks + 4 * kq;
        __half2 p0 = *(const __half2*)sp, p1 = *(const __half2*)(sp + 2);
        float2 f0 = __half22float2(p0), f1 = __half22float2(p1);
        xa = make_float4(f0.x, f0.y, f1.x, f1.y);
      } else {
        xa = *(const float4*)((const float*)x + ((size_t)b * S + t0 + tl) * K + ks + 4 * kq);
      }
      As[rr * KTB + (kq ^ ((rr >> 2) & 7))] = xa;
      Bs[rr * KTB + (kq ^ ((rr >> 2) & 7))] =
          *(const float4*)(wihP + (size_t)(n0 + rr) * K + ks + 4 * kq);
    }
    __syncthreads();
#pragma unroll 8
    for (int kb = 0; kb < KTB; ++kb) {
      float4 a[4], bb[4];
#pragma unroll
      for (int i2 = 0; i2 < 4; ++i2) a[i2] = As[(4 * tm + i2) * KTB + (kb ^ (tm & 7))];
#pragma unroll
      for (int j = 0; j < 4; ++j) bb[j] = Bs[(4 * tn + j) * KTB + (kb ^ (tn & 7))];
#pragma unroll
      for (int i2 = 0; i2 < 4; ++i2)
#pragma unroll
        for (int j = 0; j < 4; ++j) {
          acc[i2][j] += a[i2].x * bb[j].x;
          acc[i2][j] += a[i2].y * bb[j].y;
          acc[i2][j] += a[i2].z * bb[j].z;
          acc[i2][j] += a[i2].w * bb[j].w;
        }
    }
    __syncthreads();
  }
  float4 bs = *(const float4*)(bsum + n0 + 4 * tn);
  float bv[4] = {bs.x, bs.y, bs.z, bs.w};
#pragma unroll
  for (int i2 = 0; i2 < 4; ++i2)
#pragma unroll
    for (int j = 0; j < 4; ++j)
      tile[(4 * tm + i2) * 72 + 4 * tn + j] = acc[i2][j] + bv[j];
  __syncthreads();
  {
    int sub = tid >> 6, l = tid & 63;
    int nlo = l & 15, qd = l >> 4;
#pragma unroll
    for (int it = 0; it < 4; ++it) {
      int blk = it * 4 + sub;        // (tt, cg)
      int tt = blk >> 2, cg = blk & 3;
      float4 v = *(const float4*)&tile[(tt * 16 + nlo) * 72 + cg * 16 + qd * 4];
      size_t base = (((size_t)bt * Sc + (tlb + tt)) * MT + (n0 >> 4) + cg) * 256;
      *(float4*)&preT[base + (size_t)l * 4] = v;
    }
  }
}

// Weight-stationary recurrent scan. 16 WGs x 16 batch rows, 512 threads (8 waves).
// Wave w owns m-tiles [w*MTW, (w+1)*MTW). A-frags: k-tiles < KTREG in registers,
// rest in LDS. h transported via LDS in exact B-frag layout; c in LDS lane slots.
template <int H, int KTREG, bool FINAL>
__global__ __launch_bounds__(512) void scan_mfma(
    const uint4* __restrict__ wpack, const f32x4* __restrict__ preT,
    __half* __restrict__ xout, float* __restrict__ out,
    const unsigned* __restrict__ wlp, const float* __restrict__ blp,
    float* __restrict__ sth, float* __restrict__ stc,
    int Sc, int t0, int first) {
  constexpr int MT = H / 4;      // m-tiles (16 rows each), rows = 4H
  constexpr int KT = H / 32;     // k-tiles
  constexpr int MTW = MT / 8;    // m-tiles per wave
  constexpr int KTL = (KT > KTREG) ? (KT - KTREG) : 0;
  constexpr int HP = H + 8;      // padded hb row (halves)

  __shared__ uint4 lds_a[(KTL > 0) ? MT * KTL * 64 : 1];
  __shared__ __half hb[16 * HP];
  __shared__ float c_lds[MT * 64];
  __shared__ unsigned wls[FINAL ? H / 2 : 1];

  const int tid = threadIdx.x;
  const int w = tid >> 6, lane = tid & 63;
  const int n16 = lane & 15, quad = lane >> 4;
  const int bt = blockIdx.x, b0 = bt * 16;

  if constexpr (KTL > 0) {
    for (int i = tid; i < MT * KTL * 64; i += 512) {
      int l = i & 63, fk = i >> 6;
      int mt = fk / KTL, kk = fk % KTL;
      lds_a[i] = wpack[(size_t)(mt * KT + KTREG + kk) * 64 + l];
    }
  }
  uint4 areg[MTW][KTREG];
#pragma unroll
  for (int im = 0; im < MTW; ++im)
#pragma unroll
    for (int kt = 0; kt < KTREG; ++kt)
      areg[im][kt] = wpack[(size_t)((w * MTW + im) * KT + kt) * 64 + lane];

  if constexpr (FINAL)
    for (int i = tid; i < H / 2; i += 512) wls[i] = wlp[i];

  for (int i = tid; i < MT * 64; i += 512) {
    int mt = i >> 6, l = i & 63;
    int ch = mt * 4 + (l >> 4), n = l & 15;
    c_lds[i] = first ? 0.f : stc[(size_t)(b0 + n) * H + ch];
  }
  for (int i = tid; i < 16 * H; i += 512) {
    int n = i / H, ch = i % H;
    hb[n * HP + ch] =
        first ? __float2half_rn(0.f) : __float2half_rn(sth[(size_t)(b0 + n) * H + ch]);
  }
  __syncthreads();

  const float bl0 = FINAL ? blp[0] : 0.f;
  __half hh[MTW];

  for (int tl = 0; tl < Sc; ++tl) {
    // acc initialized from preT (pre-activations, already bias-folded, C-frag layout)
    f32x4 acc[MTW];
#pragma unroll
    for (int im = 0; im < MTW; ++im)
      acc[im] = preT[((size_t)(bt * Sc + tl) * MT + w * MTW + im) * 64 + lane];

    // output phase for step t0+tl-1 (hb currently holds h(tl-1)); overlaps mfma loads
    if (tl > 0) {
      int t_out = t0 + tl - 1;
      if constexpr (FINAL) {
        if (tid < 128) {
          int n = tid >> 3, seg = tid & 7;
          const unsigned* hrow = (const unsigned*)(hb + n * HP);
          float s = 0.f;
#pragma unroll
          for (int p = 0; p < 16; ++p) s = fdot2(hrow[seg * 16 + p], wls[seg * 16 + p], s);
          s += __shfl_xor(s, 1); s += __shfl_xor(s, 2); s += __shfl_xor(s, 4);
          if (seg == 0) out[(size_t)(b0 + n) * S + t_out] = ftanh_(s + bl0);
        }
      } else {
        if (tid < 16 * (H / 8)) {
          int n = tid / (H / 8), kq = tid % (H / 8);
          uint4 v = *(const uint4*)(hb + n * HP + kq * 8);
          *(uint4*)(xout + ((size_t)(b0 + n) * S + t_out) * H + kq * 8) = v;
        }
      }
    }

    // mfma k-loop: registered k-tiles then LDS k-tiles
#pragma unroll
    for (int kt = 0; kt < KTREG; ++kt) {
      f16x8 bfrag = as_f16x8(*(const uint4*)(hb + n16 * HP + kt * 32 + quad * 8));
#pragma unroll
      for (int im = 0; im < MTW; ++im)
        acc[im] = __builtin_amdgcn_mfma_f32_16x16x32_f16(as_f16x8(areg[im][kt]), bfrag,
                                                         acc[im], 0, 0, 0);
    }
    if constexpr (KTL > 0) {
#pragma unroll
      for (int kt = KTREG; kt < KT; ++kt) {
        f16x8 bfrag = as_f16x8(*(const uint4*)(hb + n16 * HP + kt * 32 + quad * 8));
#pragma unroll
        for (int im = 0; im < MTW; ++im) {
          uint4 araw = lds_a[((w * MTW + im) * KTL + (kt - KTREG)) * 64 + lane];
          acc[im] = __builtin_amdgcn_mfma_f32_16x16x32_f16(as_f16x8(araw), bfrag,
                                                           acc[im], 0, 0, 0);
        }
      }
    }

    // gates: lane holds (i,f,g,o) of one channel per m-tile
#pragma unroll
    for (int im = 0; im < MTW; ++im) {
      int mt = w * MTW + im;
      float co = c_lds[mt * 64 + lane];
      float gi = fsig(acc[im][0]);
      float gf = fsig(acc[im][1]);
      float gg = ftanh_(acc[im][2]);
      float go = fsig(acc[im][3]);
      float cn = gf * co + gi * gg;
      c_lds[mt * 64 + lane] = cn;
      hh[im] = __float2half_rn(go * ftanh_(cn));
    }
    __syncthreads();  // A: all hb(tl-1) reads done
#pragma unroll
    for (int im = 0; im < MTW; ++im)
      hb[n16 * HP + (w * MTW + im) * 4 + quad] = hh[im];
    __syncthreads();  // B: hb(tl) ready
  }

  // tail output for t0+Sc-1
  {
    int t_out = t0 + Sc - 1;
    if constexpr (FINAL) {
      if (tid < 128) {
        int n = tid >> 3, seg = tid & 7;
        const unsigned* hrow = (const unsigned*)(hb + n * HP);
        float s = 0.f;
#pragma unroll
        for (int p = 0; p < 16; ++p) s = fdot2(hrow[seg * 16 + p], wls[seg * 16 + p], s);
        s += __shfl_xor(s, 1); s += __shfl_xor(s, 2); s += __shfl_xor(s, 4);
        if (seg == 0) out[(size_t)(b0 + n) * S + t_out] = ftanh_(s + bl0);
      }
    } else {
      if (tid < 16 * (H / 8)) {
        int n = tid / (H / 8), kq = tid % (H / 8);
        uint4 v = *(const uint4*)(hb + n * HP + kq * 8);
        *(uint4*)(xout + ((size_t)(b0 + n) * S + t_out) * H + kq * 8) = v;
      }
    }
  }

  // carry state to next chunk
  for (int i = tid; i < MT * 64; i += 512) {
    int mt = i >> 6, l = i & 63;
    int ch = mt * 4 + (l >> 4), n = l & 15;
    stc[(size_t)(b0 + n) * H + ch] = c_lds[i];
  }
  for (int i = tid; i < 16 * H; i += 512) {
    int n = i / H, ch = i % H;
    sth[(size_t)(b0 + n) * H + ch] = __half2float(hb[n * HP + ch]);
  }
}

extern "C" void kernel_launch(void* const* d_in, const int* in_sizes, int n_in,
                              void* d_out, int out_size, void* d_ws, size_t ws_size,
                              hipStream_t stream) {
  (void)in_sizes; (void)n_in; (void)out_size;
  const float* noise = (const float*)d_in[0];
  const float* Wih0 = (const float*)d_in[1];
  const float* Whh0 = (const float*)d_in[2];
  const float* bih0 = (const float*)d_in[3];
  const float* bhh0 = (const float*)d_in[4];
  const float* Wih1 = (const float*)d_in[5];
  const float* Whh1 = (const float*)d_in[6];
  const float* bih1 = (const float*)d_in[7];
  const float* bhh1 = (const float*)d_in[8];
  const float* Wih2 = (const float*)d_in[9];
  const float* Whh2 = (const float*)d_in[10];
  const float* bih2 = (const float*)d_in[11];
  const float* bhh2 = (const float*)d_in[12];
  const float* Wl = (const float*)d_in[13];
  const float* bl = (const float*)d_in[14];
  float* out = (float*)d_out;

  char* p = (char*)d_ws;
  auto alloc = [&](size_t bytes) {
    char* r = p;
    p += (bytes + 255) & ~(size_t)255;
    return r;
  };
  // fragment-packed Whh (fp16)
  uint4* wp0 = (uint4*)alloc((size_t)16 * 2 * 64 * 16);
  uint4* wp1 = (uint4*)alloc((size_t)32 * 4 * 64 * 16);
  uint4* wp2 = (uint4*)alloc((size_t)64 * 8 * 64 * 16);
  // permuted Wih + bias sums
  float* wihP0 = (float*)alloc((size_t)256 * 32 * 4);
  float* bs0 = (float*)alloc(256 * 4);
  float* wihP1 = (float*)alloc((size_t)512 * 64 * 4);
  float* bs1 = (float*)alloc(512 * 4);
  float* wihP2 = (float*)alloc((size_t)1024 * 128 * 4);
  float* bs2 = (float*)alloc(1024 * 4);
  unsigned* wlp = (unsigned*)alloc(128 * 4);
  // state carry
  float* sh0 = (float*)alloc((size_t)B * H0 * 4);
  float* sc0 = (float*)alloc((size_t)B * H0 * 4);
  float* sh1 = (float*)alloc((size_t)B * H1 * 4);
  float* sc1 = (float*)alloc((size_t)B * H1 * 4);
  float* sh2 = (float*)alloc((size_t)B * H2 * 4);
  float* sc2 = (float*)alloc((size_t)B * H2 * 4);
  // inter-layer activations (fp16)
  __half* x1 = (__half*)alloc((size_t)B * S * H0 * 2);
  __half* x2 = (__half*)alloc((size_t)B * S * H1 * 2);
  size_t fixed = (size_t)(p - (char*)d_ws);
  int Sc = 128;  // time-chunk keeps the preT buffer bounded / L3-resident
  while (Sc > 16 && fixed + (size_t)B * Sc * 1024 * 4 > ws_size) Sc >>= 1;
  float* preT = (float*)alloc((size_t)B * Sc * 1024 * 4);

  // ---- weight packing (re-done every call; deterministic) ----
  pack_whh_frag<<<(16 * 2 * 64 + 255) / 256, 256, 0, stream>>>(Whh0, wp0, H0, 16, 2);
  pack_whh_frag<<<(32 * 4 * 64 + 255) / 256, 256, 0, stream>>>(Whh1, wp1, H1, 32, 4);
  pack_whh_frag<<<(64 * 8 * 64 + 255) / 256, 256, 0, stream>>>(Whh2, wp2, H2, 64, 8);
  pack_wih<<<(256 * 32 + 255) / 256, 256, 0, stream>>>(Wih0, bih0, bhh0, wihP0, bs0, H0, 32);
  pack_wih<<<(512 * 64 + 255) / 256, 256, 0, stream>>>(Wih1, bih1, bhh1, wihP1, bs1, H1, 64);
  pack_wih<<<(1024 * 128 + 255) / 256, 256, 0, stream>>>(Wih2, bih2, bhh2, wihP2, bs2, H2, 128);
  pack_wl<<<1, 128, 0, stream>>>(Wl, wlp, 128);

  for (int c = 0; c < S / Sc; ++c) {
    int t0 = c * Sc;
    dim3 g0(16 * (Sc / 4), 4), g1(16 * (Sc / 4), 8), g2(16 * (Sc / 4), 16);
    ingemm<float, 32><<<g0, 256, 0, stream>>>(noise, wihP0, bs0, preT, 16, Sc, t0);
    scan_mfma<64, 2, false><<<16, 512, 0, stream>>>(
        wp0, (const f32x4*)preT, x1, nullptr, nullptr, nullptr, sh0, sc0, Sc, t0, c == 0);
    ingemm<__half, 64><<<g1, 256, 0, stream>>>(x1, wihP1, bs1, preT, 32, Sc, t0);
    scan_mfma<128, 4, false><<<16, 512, 0, stream>>>(
        wp1, (const f32x4*)preT, x2, nullptr, nullptr, nullptr, sh1, sc1, Sc, t0, c == 0);
    ingemm<__half, 128><<<g2, 256, 0, stream>>>(x2, wihP2, bs2, preT, 64, Sc, t0);
    scan_mfma<256, 6, true><<<16, 512, 0, stream>>>(
        wp2, (const f32x4*)preT, nullptr, out, wlp, bl, sh2, sc2, Sc, t0, c == 0);
  }
}

// Round 4
// 2996.970 us; speedup vs baseline: 2.4695x; 1.2994x over previous
//
#include <hip/hip_runtime.h>
#include <hip/hip_fp16.h>

#define DEVINL __device__ __forceinline__

constexpr int B = 256, S = 512;
constexpr int H0 = 64, H1 = 128, H2 = 256;

typedef _Float16 f16x8 __attribute__((ext_vector_type(8)));
typedef float f32x4 __attribute__((ext_vector_type(4)));
typedef _Float16 h2v __attribute__((ext_vector_type(2)));

DEVINL float fexp2(float x) { return __builtin_amdgcn_exp2f(x); }
DEVINL float frcp(float x) { return __builtin_amdgcn_rcpf(x); }
DEVINL float fsig(float x) { return frcp(1.f + fexp2(-1.44269504088896f * x)); }
DEVINL float ftanh_(float x) { return 1.f - 2.f * frcp(1.f + fexp2(2.88539008177793f * x)); }
DEVINL h2v as_h2(unsigned u) { union { unsigned u; h2v h; } x; x.u = u; return x.h; }
DEVINL float fdot2(unsigned a, unsigned b, float c) {
  return __builtin_amdgcn_fdot2(as_h2(a), as_h2(b), c, false);
}
union FU { uint4 u; f16x8 h; };
DEVINL f16x8 as_f16x8(uint4 u) { FU x; x.u = u; return x.h; }

// Row permutation: r' = mt*16 + quad*4 + reg  ->  channel = r'>>2, gate = r'&3.
// orig torch row = gate*Hch + channel. One lane of the C-frag then holds one
// channel's (i,f,g,o) quad (C: col=lane&15, row=(lane>>4)*4+reg).

// Pack W (fp32 [4*Hch][Kdim], torch gate rows) into fp16 A-frag order:
// wp[(mt*KT+kt)*64+lane] = 8 halves of W'[mt*16+(lane&15)][kt*32+(lane>>4)*8+j]
__global__ __launch_bounds__(256) void pack_frag(const float* __restrict__ w,
    uint4* __restrict__ wp, int Hch, int Kdim, int MT, int KT) {
  int o = blockIdx.x * 256 + threadIdx.x;
  if (o >= MT * KT * 64) return;
  int lane = o & 63, fk = o >> 6;
  int kt = fk % KT, mt = fk / KT;
  int rp = mt * 16 + (lane & 15);
  int orig = (rp & 3) * Hch + (rp >> 2);
  int k0 = kt * 32 + (lane >> 4) * 8;
  unsigned r[4];
#pragma unroll
  for (int p = 0; p < 4; ++p) {
    unsigned lo = __half_as_ushort(__float2half_rn(w[(size_t)orig * Kdim + k0 + 2 * p]));
    unsigned hi = __half_as_ushort(__float2half_rn(w[(size_t)orig * Kdim + k0 + 2 * p + 1]));
    r[p] = lo | (hi << 16);
  }
  uint4 v; v.x = r[0]; v.y = r[1]; v.z = r[2]; v.w = r[3];
  wp[o] = v;
}

__global__ __launch_bounds__(256) void pack_bias(const float* __restrict__ bih,
    const float* __restrict__ bhh, float* __restrict__ bs, int Hch) {
  int rp = blockIdx.x * 256 + threadIdx.x;
  if (rp >= 4 * Hch) return;
  int orig = (rp & 3) * Hch + (rp >> 2);
  bs[rp] = bih[orig] + bhh[orig];
}

__global__ void pack_wl(const float* __restrict__ wl, unsigned* __restrict__ wlp, int n) {
  int i = threadIdx.x;
  if (i < n) {
    unsigned lo = __half_as_ushort(__float2half_rn(wl[2 * i]));
    unsigned hi = __half_as_ushort(__float2half_rn(wl[2 * i + 1]));
    wlp[i] = lo | (hi << 16);
  }
}

__global__ __launch_bounds__(256) void f2h(const float* __restrict__ x,
                                           __half* __restrict__ y, int n8) {
  int i = blockIdx.x * 256 + threadIdx.x;
  if (i >= n8) return;
  float4 a = *(const float4*)(x + i * 8);
  float4 b = *(const float4*)(x + i * 8 + 4);
  __half h[8];
  h[0] = __float2half_rn(a.x); h[1] = __float2half_rn(a.y);
  h[2] = __float2half_rn(a.z); h[3] = __float2half_rn(a.w);
  h[4] = __float2half_rn(b.x); h[5] = __float2half_rn(b.y);
  h[6] = __float2half_rn(b.z); h[7] = __float2half_rn(b.w);
  *(uint4*)(y + i * 8) = *(const uint4*)h;
}

// MFMA input GEMM: preT[((bt*Sc+tl)*MT+mt)*64+lane] (C-frag f32x4) =
//   x[16 batch] @ WihP^T + bias.  Grid (bt, Sc/8, MT/16); 256 thr (4 waves).
template <int KT>
__global__ __launch_bounds__(256) void ingemm_mfma(const __half* __restrict__ x,
    const uint4* __restrict__ wp, const float* __restrict__ bs,
    f32x4* __restrict__ preT, int MT, int Sc, int t0) {
  constexpr int K = KT * 32;
  const int tid = threadIdx.x, w = tid >> 6, lane = tid & 63;
  const int n16 = lane & 15, quad = lane >> 4;
  const int bt = blockIdx.x, b0 = bt * 16;
  const int tlb = blockIdx.y * 8;
  const int mb = blockIdx.z * 16;

  uint4 areg[4][KT];
#pragma unroll
  for (int im = 0; im < 4; ++im)
#pragma unroll
    for (int kt = 0; kt < KT; ++kt)
      areg[im][kt] = wp[((size_t)(mb + w * 4 + im) * KT + kt) * 64 + lane];
  f32x4 bini[4];
#pragma unroll
  for (int im = 0; im < 4; ++im)
    bini[im] = *(const f32x4*)(bs + (mb + w * 4 + im) * 16 + quad * 4);

  for (int tt = 0; tt < 8; ++tt) {
    int t = t0 + tlb + tt;
    const __half* xr = x + ((size_t)(b0 + n16) * S + t) * K + quad * 8;
    uint4 bfr[KT];
#pragma unroll
    for (int kt = 0; kt < KT; ++kt) bfr[kt] = *(const uint4*)(xr + kt * 32);
    f32x4 acc[4];
#pragma unroll
    for (int im = 0; im < 4; ++im) acc[im] = bini[im];
#pragma unroll
    for (int kt = 0; kt < KT; ++kt)
#pragma unroll
      for (int im = 0; im < 4; ++im)
        acc[im] = __builtin_amdgcn_mfma_f32_16x16x32_f16(as_f16x8(areg[im][kt]),
                                                         as_f16x8(bfr[kt]), acc[im], 0, 0, 0);
#pragma unroll
    for (int im = 0; im < 4; ++im)
      preT[((size_t)(bt * Sc + tlb + tt) * MT + mb + w * 4 + im) * 64 + lane] = acc[im];
  }
}

// Weight-stationary recurrent scan, weights fully in registers.
// SPLIT=1: one WG per 16-batch group. SPLIT=2: two WGs split the m-dim;
// per-step h exchange via global xh (parity ping-pong) + device-scope flags.
template <int H, int SPLIT, bool FINAL>
__global__ __launch_bounds__(512) void scan_mfma(
    const uint4* __restrict__ wp, const f32x4* __restrict__ preT,
    __half* __restrict__ xout, float* __restrict__ out,
    const unsigned* __restrict__ wlp, const float* __restrict__ blp,
    float* __restrict__ sth, float* __restrict__ stc,
    unsigned* __restrict__ xh, int* __restrict__ flags,
    int Sc, int t0, int first) {
  constexpr int MT = H / 4;          // total m-tiles
  constexpr int MTO = MT / SPLIT;    // owned m-tiles
  constexpr int MTW = MTO / 8;       // per wave
  constexpr int KT = H / 32;
  constexpr int HP = H + 8;
  constexpr int CH_OWN = MTO * 4;    // owned channels

  __shared__ __half hb[16 * HP];
  __shared__ unsigned wls[FINAL ? H / 2 : 1];

  const int tid = threadIdx.x, w = tid >> 6, lane = tid & 63;
  const int n16 = lane & 15, quad = lane >> 4;
  int bt, half;
  if constexpr (SPLIT == 2) { bt = blockIdx.x & 15; half = blockIdx.x >> 4; }
  else { bt = blockIdx.x; half = 0; }
  const int b0 = bt * 16;
  const int mbase = half * MTO;

  uint4 areg[MTW][KT];
#pragma unroll
  for (int im = 0; im < MTW; ++im)
#pragma unroll
    for (int kt = 0; kt < KT; ++kt)
      areg[im][kt] = wp[((size_t)(mbase + w * MTW + im) * KT + kt) * 64 + lane];

  if constexpr (FINAL)
    for (int i = tid; i < H / 2; i += 512) wls[i] = wlp[i];

  float cst[MTW];
#pragma unroll
  for (int im = 0; im < MTW; ++im) {
    int ch = (mbase + w * MTW + im) * 4 + quad;
    cst[im] = first ? 0.f : stc[(size_t)(b0 + n16) * H + ch];
  }
  for (int i = tid; i < 16 * H; i += 512) {
    int n = i / H, ch = i % H;
    hb[n * HP + ch] = first ? __float2half_rn(0.f)
                            : __float2half_rn(sth[(size_t)(b0 + n) * H + ch]);
  }
  __syncthreads();

  const float bl0 = FINAL ? blp[0] : 0.f;

  f32x4 nxt[MTW];
#pragma unroll
  for (int im = 0; im < MTW; ++im)
    nxt[im] = preT[((size_t)(bt * Sc) * MT + mbase + w * MTW + im) * 64 + lane];

  for (int tl = 0; tl < Sc; ++tl) {
    f32x4 acc[MTW];
#pragma unroll
    for (int im = 0; im < MTW; ++im) acc[im] = nxt[im];
    if (tl + 1 < Sc) {  // prefetch next step's preT (consumed next iter)
#pragma unroll
      for (int im = 0; im < MTW; ++im)
        nxt[im] = preT[((size_t)(bt * Sc + tl + 1) * MT + mbase + w * MTW + im) * 64 + lane];
    }

    // output phase for step tl-1 (hb holds completed h(tl-1)); overlaps compute
    if (tl > 0) {
      int t_out = t0 + tl - 1;
      if constexpr (FINAL) {
        if (half == 0 && tid < 128) {
          int n = tid >> 3, seg = tid & 7;
          const unsigned* hrow = (const unsigned*)(hb + n * HP);
          float s = 0.f;
#pragma unroll
          for (int p = 0; p < 16; ++p) s = fdot2(hrow[seg * 16 + p], wls[seg * 16 + p], s);
          s += __shfl_xor(s, 1); s += __shfl_xor(s, 2); s += __shfl_xor(s, 4);
          if (seg == 0) out[(size_t)(b0 + n) * S + t_out] = ftanh_(s + bl0);
        }
      } else {
        if (tid < 16 * (H / 8)) {
          int n = tid / (H / 8), kq = tid % (H / 8);
          uint4 v = *(const uint4*)(hb + n * HP + kq * 8);
          *(uint4*)(xout + ((size_t)(b0 + n) * S + t_out) * H + kq * 8) = v;
        }
      }
    }

    // MFMA k-loop (weights in regs, B-frags from hb LDS)
#pragma unroll
    for (int kt = 0; kt < KT; ++kt) {
      f16x8 bfrag = as_f16x8(*(const uint4*)(hb + n16 * HP + kt * 32 + quad * 8));
#pragma unroll
      for (int im = 0; im < MTW; ++im)
        acc[im] = __builtin_amdgcn_mfma_f32_16x16x32_f16(as_f16x8(areg[im][kt]), bfrag,
                                                         acc[im], 0, 0, 0);
    }

    // gates (lane holds one channel's i,f,g,o per m-tile)
    __half hh[MTW];
#pragma unroll
    for (int im = 0; im < MTW; ++im) {
      float gi = fsig(acc[im][0]);
      float gf = fsig(acc[im][1]);
      float gg = ftanh_(acc[im][2]);
      float go = fsig(acc[im][3]);
      float cn = gf * cst[im] + gi * gg;
      cst[im] = cn;
      hh[im] = __float2half_rn(go * ftanh_(cn));
    }
    __syncthreads();  // A: hb(tl-1) reads done
#pragma unroll
    for (int im = 0; im < MTW; ++im)
      hb[n16 * HP + (mbase + w * MTW + im) * 4 + quad] = hh[im];

    if constexpr (SPLIT == 2) {
      __syncthreads();  // own half of hb complete
      const int s = t0 + tl + 1;
      const int par = s & 1;
      unsigned* dst = xh + (((size_t)par * 16 + bt) * 2 + half) * (CH_OWN * 8);
      for (int i = tid; i < 16 * (CH_OWN / 2); i += 512) {
        int n = i >> 6, c2 = i & 63;
        unsigned v = *(const unsigned*)(hb + n * HP + half * CH_OWN + c2 * 2);
        __hip_atomic_store(dst + i, v, __ATOMIC_RELAXED, __HIP_MEMORY_SCOPE_AGENT);
      }
      __syncthreads();  // all waves' exports issued (waves drain vm before barrier)
      if (tid == 0) {
        __threadfence();
        __hip_atomic_store(&flags[bt * 2 + half], s, __ATOMIC_RELEASE,
                           __HIP_MEMORY_SCOPE_AGENT);
        while (__hip_atomic_load(&flags[bt * 2 + (1 - half)], __ATOMIC_ACQUIRE,
                                 __HIP_MEMORY_SCOPE_AGENT) < s)
          __builtin_amdgcn_s_sleep(8);
      }
      __syncthreads();  // peer data ready
      const unsigned* src = xh + (((size_t)par * 16 + bt) * 2 + (1 - half)) * (CH_OWN * 8);
      for (int i = tid; i < 16 * (CH_OWN / 2); i += 512) {
        unsigned v = __hip_atomic_load(src + i, __ATOMIC_RELAXED, __HIP_MEMORY_SCOPE_AGENT);
        int n = i >> 6, c2 = i & 63;
        *(unsigned*)(hb + n * HP + (1 - half) * CH_OWN + c2 * 2) = v;
      }
      __syncthreads();  // hb(tl) complete
    } else {
      __syncthreads();  // B: hb(tl) complete
    }
  }

  // tail output for t0+Sc-1
  {
    int t_out = t0 + Sc - 1;
    if constexpr (FINAL) {
      if (half == 0 && tid < 128) {
        int n = tid >> 3, seg = tid & 7;
        const unsigned* hrow = (const unsigned*)(hb + n * HP);
        float s = 0.f;
#pragma unroll
        for (int p = 0; p < 16; ++p) s = fdot2(hrow[seg * 16 + p], wls[seg * 16 + p], s);
        s += __shfl_xor(s, 1); s += __shfl_xor(s, 2); s += __shfl_xor(s, 4);
        if (seg == 0) out[(size_t)(b0 + n) * S + t_out] = ftanh_(s + bl0);
      }
    } else {
      if (tid < 16 * (H / 8)) {
        int n = tid / (H / 8), kq = tid % (H / 8);
        uint4 v = *(const uint4*)(hb + n * HP + kq * 8);
        *(uint4*)(xout + ((size_t)(b0 + n) * S + t_out) * H + kq * 8) = v;
      }
    }
  }

  // carry state (sth full range — duplicate identical writes for SPLIT=2 are benign)
  for (int i = tid; i < 16 * H; i += 512) {
    int n = i / H, ch = i % H;
    sth[(size_t)(b0 + n) * H + ch] = __half2float(hb[n * HP + ch]);
  }
#pragma unroll
  for (int im = 0; im < MTW; ++im) {
    int ch = (mbase + w * MTW + im) * 4 + quad;
    stc[(size_t)(b0 + n16) * H + ch] = cst[im];
  }
}

extern "C" void kernel_launch(void* const* d_in, const int* in_sizes, int n_in,
                              void* d_out, int out_size, void* d_ws, size_t ws_size,
                              hipStream_t stream) {
  (void)in_sizes; (void)n_in; (void)out_size;
  const float* noise = (const float*)d_in[0];
  const float* Wih0 = (const float*)d_in[1];
  const float* Whh0 = (const float*)d_in[2];
  const float* bih0 = (const float*)d_in[3];
  const float* bhh0 = (const float*)d_in[4];
  const float* Wih1 = (const float*)d_in[5];
  const float* Whh1 = (const float*)d_in[6];
  const float* bih1 = (const float*)d_in[7];
  const float* bhh1 = (const float*)d_in[8];
  const float* Wih2 = (const float*)d_in[9];
  const float* Whh2 = (const float*)d_in[10];
  const float* bih2 = (const float*)d_in[11];
  const float* bhh2 = (const float*)d_in[12];
  const float* Wl = (const float*)d_in[13];
  const float* bl = (const float*)d_in[14];
  float* out = (float*)d_out;

  char* p = (char*)d_ws;
  auto alloc = [&](size_t bytes) {
    char* r = p;
    p += (bytes + 255) & ~(size_t)255;
    return r;
  };
  // A-frag packed weights (fp16): recurrent + input
  uint4* wpH0 = (uint4*)alloc((size_t)16 * 2 * 1024);
  uint4* wpH1 = (uint4*)alloc((size_t)32 * 4 * 1024);
  uint4* wpH2 = (uint4*)alloc((size_t)64 * 8 * 1024);
  uint4* wpI0 = (uint4*)alloc((size_t)16 * 1 * 1024);
  uint4* wpI1 = (uint4*)alloc((size_t)32 * 2 * 1024);
  uint4* wpI2 = (uint4*)alloc((size_t)64 * 4 * 1024);
  float* bs0 = (float*)alloc(256 * 4);
  float* bs1 = (float*)alloc(512 * 4);
  float* bs2 = (float*)alloc(1024 * 4);
  unsigned* wlp = (unsigned*)alloc(128 * 4);
  // state carry
  float* sh0 = (float*)alloc((size_t)B * H0 * 4);
  float* sc0 = (float*)alloc((size_t)B * H0 * 4);
  float* sh1 = (float*)alloc((size_t)B * H1 * 4);
  float* sc1 = (float*)alloc((size_t)B * H1 * 4);
  float* sh2 = (float*)alloc((size_t)B * H2 * 4);
  float* sc2 = (float*)alloc((size_t)B * H2 * 4);
  // activations (fp16)
  __half* x0 = (__half*)alloc((size_t)B * S * 32 * 2);
  __half* x1 = (__half*)alloc((size_t)B * S * H0 * 2);
  __half* x2 = (__half*)alloc((size_t)B * S * H1 * 2);
  // cross-WG exchange buffers + flags (layer 2)
  unsigned* xh = (unsigned*)alloc((size_t)2 * 16 * 2 * 1024 * 4);
  int* flags = (int*)alloc(64 * 4);
  size_t fixed = (size_t)(p - (char*)d_ws);
  int Sc = 128;  // time-chunk keeps preT bounded / L3-resident
  while (Sc > 16 && fixed + (size_t)B * Sc * 1024 * 4 > ws_size) Sc >>= 1;
  float* preT = (float*)alloc((size_t)B * Sc * 1024 * 4);

  // ---- packing (every call; deterministic) ----
  pack_frag<<<(16 * 2 * 64 + 255) / 256, 256, 0, stream>>>(Whh0, wpH0, 64, 64, 16, 2);
  pack_frag<<<(32 * 4 * 64 + 255) / 256, 256, 0, stream>>>(Whh1, wpH1, 128, 128, 32, 4);
  pack_frag<<<(64 * 8 * 64 + 255) / 256, 256, 0, stream>>>(Whh2, wpH2, 256, 256, 64, 8);
  pack_frag<<<(16 * 1 * 64 + 255) / 256, 256, 0, stream>>>(Wih0, wpI0, 64, 32, 16, 1);
  pack_frag<<<(32 * 2 * 64 + 255) / 256, 256, 0, stream>>>(Wih1, wpI1, 128, 64, 32, 2);
  pack_frag<<<(64 * 4 * 64 + 255) / 256, 256, 0, stream>>>(Wih2, wpI2, 256, 128, 64, 4);
  pack_bias<<<1, 256, 0, stream>>>(bih0, bhh0, bs0, 64);
  pack_bias<<<2, 256, 0, stream>>>(bih1, bhh1, bs1, 128);
  pack_bias<<<4, 256, 0, stream>>>(bih2, bhh2, bs2, 256);
  pack_wl<<<1, 128, 0, stream>>>(Wl, wlp, 128);
  f2h<<<(B * S * 32 / 8 + 255) / 256, 256, 0, stream>>>(noise, x0, B * S * 32 / 8);

  for (int c = 0; c < S / Sc; ++c) {
    int t0 = c * Sc;
    ingemm_mfma<1><<<dim3(16, Sc / 8, 1), 256, 0, stream>>>(x0, wpI0, bs0,
                                                            (f32x4*)preT, 16, Sc, t0);
    scan_mfma<64, 1, false><<<16, 512, 0, stream>>>(
        wpH0, (const f32x4*)preT, x1, nullptr, nullptr, nullptr, sh0, sc0,
        nullptr, nullptr, Sc, t0, c == 0);
    ingemm_mfma<2><<<dim3(16, Sc / 8, 2), 256, 0, stream>>>(x1, wpI1, bs1,
                                                            (f32x4*)preT, 32, Sc, t0);
    scan_mfma<128, 1, false><<<16, 512, 0, stream>>>(
        wpH1, (const f32x4*)preT, x2, nullptr, nullptr, nullptr, sh1, sc1,
        nullptr, nullptr, Sc, t0, c == 0);
    ingemm_mfma<4><<<dim3(16, Sc / 8, 4), 256, 0, stream>>>(x2, wpI2, bs2,
                                                            (f32x4*)preT, 64, Sc, t0);
    scan_mfma<256, 2, true><<<32, 512, 0, stream>>>(
        wpH2, (const f32x4*)preT, nullptr, out, wlp, bl, sh2, sc2,
        xh, flags, Sc, t0, c == 0);
  }
}